// Round 1
// baseline (206.600 us; speedup 1.0000x reference)
//
#include <hip/hip_runtime.h>

// KPConvInterSO3: N=16000 queries, M=16000 support, NB=32 neighbors,
// A=4 anchors, K=15 kernel points, CIN=COUT=32. All fp32.
// Block = 256 threads handles Q=2 queries. 8000 blocks.

#define NBH 32

static __device__ __forceinline__ void fma4(float4& a, float s, const float4& v) {
    a.x = fmaf(s, v.x, a.x);
    a.y = fmaf(s, v.y, a.y);
    a.z = fmaf(s, v.z, a.z);
    a.w = fmaf(s, v.w, a.w);
}

__global__ __launch_bounds__(256) void kpconv_kernel(
    const float* __restrict__ q_pts,    // [N,3]
    const float* __restrict__ s_pts,    // [M,3]
    const int*   __restrict__ inds,     // [N,32]
    const float* __restrict__ x,        // [M,4,32]
    const float* __restrict__ kp,       // [15,3]
    const float* __restrict__ anchors,  // [4,3,3]
    const float* __restrict__ W,        // [15,32,32]
    float*       __restrict__ out)      // [N,4,32]
{
    // xs: [2][32][128] floats (32KB); after phase 3 reused as wf [2][4][16][32]
    __shared__ __align__(16) float xs[8192];
    // aw: 8 slices (q*4+a) of stride 516 (pad +4 breaks pow2 bank stride);
    // after phase 4 reused as reduction buffer (1024 floats)
    __shared__ __align__(16) float aw[4128];
    __shared__ __align__(16) float nbr[256];   // [2][32] float4: (dx,dy,dz,|d|^2)
    __shared__ __align__(16) float rk[256];    // [4][16] float4: (rx,ry,rz,|r|^2)
    __shared__ int sidx[64];

    const int t  = threadIdx.x;
    const int n0 = blockIdx.x * 2;

    // ---------------- Phase 0: neighbors + rotated kernel points ----------------
    if (t < 64) {
        const int q = t >> 5, b = t & 31;
        const int idx = inds[(n0 + q) * NBH + b];
        sidx[t] = idx;
        const float qx = q_pts[(n0 + q) * 3 + 0];
        const float qy = q_pts[(n0 + q) * 3 + 1];
        const float qz = q_pts[(n0 + q) * 3 + 2];
        const float nx = s_pts[idx * 3 + 0] - qx;
        const float ny = s_pts[idx * 3 + 1] - qy;
        const float nz = s_pts[idx * 3 + 2] - qz;
        float4 v;
        v.x = nx; v.y = ny; v.z = nz;
        v.w = nx * nx + ny * ny + nz * nz;
        *(float4*)&nbr[t * 4] = v;
    } else if (t < 124) {
        const int j = t - 64;
        const int a = j / 15, k = j - a * 15;
        const float kx = kp[k * 3 + 0], ky = kp[k * 3 + 1], kz = kp[k * 3 + 2];
        const float* R = anchors + a * 9;
        float4 v;
        v.x = R[0] * kx + R[1] * ky + R[2] * kz;
        v.y = R[3] * kx + R[4] * ky + R[5] * kz;
        v.z = R[6] * kx + R[7] * ky + R[8] * kz;
        v.w = v.x * v.x + v.y * v.y + v.z * v.z;
        *(float4*)&rk[(a * 16 + k) * 4] = v;
    }
    __syncthreads();

    // ---------------- Phase 1: aw[s][b][k16], s = q*4+a ----------------
    {
        const int q = t >> 7, a = (t >> 5) & 3, b = t & 31;
        const int s = q * 4 + a;
        const float4 nb4 = *(const float4*)&nbr[(q * 32 + b) * 4];
        float w[16];
        #pragma unroll
        for (int k = 0; k < 15; ++k) {
            const float4 r4 = *(const float4*)&rk[(a * 16 + k) * 4];
            const float sq = nb4.w + r4.w
                - 2.0f * (nb4.x * r4.x + nb4.y * r4.y + nb4.z * r4.z);
            const float d = sqrtf(fmaxf(sq, 1e-12f));
            w[k] = fmaxf(1.0f - d * (1.0f / 0.6f), 0.0f);
        }
        w[15] = 0.0f;
        float* awp = &aw[s * 516 + b * 16];
        *(float4*)&awp[0]  = make_float4(w[0],  w[1],  w[2],  w[3]);
        *(float4*)&awp[4]  = make_float4(w[4],  w[5],  w[6],  w[7]);
        *(float4*)&awp[8]  = make_float4(w[8],  w[9],  w[10], w[11]);
        *(float4*)&awp[12] = make_float4(w[12], w[13], w[14], w[15]);
    }

    // ---------------- Phase 2: gather x -> xs[q][b][a*32+c] ----------------
    {
        #pragma unroll
        for (int i = 0; i < 8; ++i) {
            const int f = t + 256 * i;        // 0..2047 float4 slots
            const int q = f >> 10;
            const int r = f & 1023;
            const int b = r >> 5, j = r & 31; // j covers (a, c4): 32 float4 per row
            const float4 v = ((const float4*)x)[sidx[q * 32 + b] * 32 + j];
            *(float4*)&xs[((q * 32 + b) * 32 + j) * 4] = v;
        }
    }
    __syncthreads();

    // ---------------- Phase 3: wf[k][c] = sum_b aw[b][k] * xs[b][c] ----------------
    // thread -> (q, kq(4 k's), a, c4(4 c's)); 4x4 register tile
    const int q3 = t >> 7, kq3 = (t >> 5) & 3, a3 = (t >> 3) & 3, c43 = t & 7;
    float4 acc0 = {0,0,0,0}, acc1 = {0,0,0,0}, acc2 = {0,0,0,0}, acc3 = {0,0,0,0};
    {
        const float* awp = &aw[(q3 * 4 + a3) * 516 + kq3 * 4];
        const float* xsp = &xs[q3 * 4096 + a3 * 32 + c43 * 4];
        #pragma unroll 4
        for (int b = 0; b < 32; ++b) {
            const float4 a4 = *(const float4*)&awp[b * 16];
            const float4 x4 = *(const float4*)&xsp[b * 128];
            fma4(acc0, a4.x, x4);
            fma4(acc1, a4.y, x4);
            fma4(acc2, a4.z, x4);
            fma4(acc3, a4.w, x4);
        }
    }
    __syncthreads();   // all xs reads complete; safe to overwrite with wf
    {
        float* wfp = &xs[((q3 * 4 + a3) * 16 + kq3 * 4) * 32 + c43 * 4];
        *(float4*)&wfp[0]  = acc0;
        *(float4*)&wfp[32] = acc1;
        *(float4*)&wfp[64] = acc2;
        *(float4*)&wfp[96] = acc3;
    }
    __syncthreads();

    // ---------------- Phase 4: out[q][a][d] = sum_{k,c} wf * W ----------------
    // thread -> (kg = wave id, q, a, d4); each wave handles its own k range
    const int kg = t >> 6, q4 = (t >> 5) & 1, a4 = (t >> 3) & 3, d4 = t & 7;
    float4 o = {0,0,0,0};
    {
        const int kbeg = kg * 4;
        const int kend = (kg == 3) ? 15 : (kbeg + 4);
        for (int k = kbeg; k < kend; ++k) {
            const float*  wfp = &xs[((q4 * 4 + a4) * 16 + k) * 32];
            const float4* Wp  = (const float4*)(W + k * 1024) + d4;
            #pragma unroll
            for (int c4 = 0; c4 < 8; ++c4) {
                const float4 w4 = *(const float4*)&wfp[c4 * 4];
                const float4 W0 = Wp[(c4 * 4 + 0) * 8];
                const float4 W1 = Wp[(c4 * 4 + 1) * 8];
                const float4 W2 = Wp[(c4 * 4 + 2) * 8];
                const float4 W3 = Wp[(c4 * 4 + 3) * 8];
                fma4(o, w4.x, W0);
                fma4(o, w4.y, W1);
                fma4(o, w4.z, W2);
                fma4(o, w4.w, W3);
            }
        }
    }
    // k-group reduction through LDS (reuse aw region; its reads ended 2 barriers ago)
    float* red = aw;
    *(float4*)&red[(((kg * 2 + q4) * 4 + a4) * 8 + d4) * 4] = o;
    __syncthreads();
    if (t < 64) {
        const int q = t >> 5, a = (t >> 3) & 3, d = t & 7;
        float4 s0 = {0,0,0,0};
        #pragma unroll
        for (int g = 0; g < 4; ++g) {
            const float4 v = *(const float4*)&red[(((g * 2 + q) * 4 + a) * 8 + d) * 4];
            s0.x += v.x; s0.y += v.y; s0.z += v.z; s0.w += v.w;
        }
        *(float4*)&out[((n0 + q) * 4 + a) * 32 + d * 4] = s0;
    }
}

extern "C" void kernel_launch(void* const* d_in, const int* in_sizes, int n_in,
                              void* d_out, int out_size, void* d_ws, size_t ws_size,
                              hipStream_t stream) {
    const float* q_pts   = (const float*)d_in[0];
    const float* s_pts   = (const float*)d_in[1];
    const int*   inds    = (const int*)d_in[2];
    const float* x       = (const float*)d_in[3];
    const float* kp      = (const float*)d_in[4];
    const float* anchors = (const float*)d_in[5];
    const float* weights = (const float*)d_in[6];
    float*       out     = (float*)d_out;

    // 16000 queries / 2 per block
    kpconv_kernel<<<dim3(8000), dim3(256), 0, stream>>>(
        q_pts, s_pts, inds, x, kp, anchors, weights, out);
}

// Round 2
// 140.703 us; speedup vs baseline: 1.4683x; 1.4683x over previous
//
#include <hip/hip_runtime.h>

// KPConvInterSO3 via MFMA. N=16000, NB=32, A=4, K=15, CIN=COUT=32.
// Block = 256 threads = 4 waves; block handles 4 queries; wave w owns anchor w.
// GEMM1 per (q,a): wf[k,c] = sum_b aw[b,k] x[b,c]   (16x32, K=32) -> 2 MFMA
// GEMM2 per a:     out[q,d] = sum_{kc} wf[q,kc] W[kc,d] (16x32, K=512) -> 32 MFMA
// W pre-permuted to B-fragment layout (bf16) in d_ws by prep_kernel.

typedef short bf16x8 __attribute__((ext_vector_type(8)));
typedef float f32x4  __attribute__((ext_vector_type(4)));

__device__ __forceinline__ unsigned short f2bf(float f) {
    unsigned u = __builtin_bit_cast(unsigned, f);
    u += 0x7FFFu + ((u >> 16) & 1u);          // round-to-nearest-even
    return (unsigned short)(u >> 16);
}

// Wp[kk][d][e] = bf16(W[k][c][d]), kcs' = kk*32+e = c*16+k (k=15 -> 0 pad).
// B-frag for GEMM2 step kk: lane reads 8 contiguous bf16 at [kk][d][quad*8].
__global__ void prep_kernel(const float* __restrict__ W, unsigned short* __restrict__ Wp) {
    const int t = threadIdx.x;
    for (int idx = t; idx < 16384; idx += 256) {
        const int kk = idx >> 10, d = (idx >> 5) & 31, e = idx & 31;
        const int kcs = kk * 32 + e;
        const int c = kcs >> 4, k = kcs & 15;
        const float v = (k < 15) ? W[(k * 32 + c) * 32 + d] : 0.0f;
        Wp[idx] = f2bf(v);
    }
}

__global__ __launch_bounds__(256) void kpconv_mfma(
    const float* __restrict__ q_pts,    // [N,3]
    const float* __restrict__ s_pts,    // [M,3]
    const int*   __restrict__ inds,     // [N,32]
    const float* __restrict__ x,        // [M,4,32]
    const float* __restrict__ kp,       // [15,3]
    const float* __restrict__ anchors,  // [4,3,3]
    const unsigned short* __restrict__ Wp, // [16][32][32] bf16 (permuted)
    float*       __restrict__ out)      // [N,4,32]
{
    // xa_s: [a][q][c][b_phys] bf16, 32KB. Per-a 4KB slice; after GEMM1 the
    // first 1KB-per-q is reused (wave-private, in order) as wf[q][c*16+k] bf16.
    __shared__ __align__(16) unsigned short xa_s[16384];
    __shared__ __align__(16) unsigned short aw_s[8192];   // [a][q][k][b] bf16, 16KB
    __shared__ __align__(16) float nbr[512];              // [q][b] float4 (dx,dy,dz,|d|^2)
    __shared__ __align__(16) float rk_s[256];             // [a][k] float4 (rx,ry,rz,|r|^2)
    __shared__ int sidx[128];                             // [q][b]

    const int t  = threadIdx.x;
    const int n0 = blockIdx.x * 4;

    // ---------------- P0: neighbors + rotated kernel points ----------------
    if (t < 128) {
        const int q = t >> 5, b = t & 31;
        const int idx = inds[(n0 + q) * 32 + b];
        sidx[t] = idx;
        const float qx = q_pts[(n0 + q) * 3 + 0];
        const float qy = q_pts[(n0 + q) * 3 + 1];
        const float qz = q_pts[(n0 + q) * 3 + 2];
        const float nx = s_pts[idx * 3 + 0] - qx;
        const float ny = s_pts[idx * 3 + 1] - qy;
        const float nz = s_pts[idx * 3 + 2] - qz;
        float4 v; v.x = nx; v.y = ny; v.z = nz; v.w = nx*nx + ny*ny + nz*nz;
        *(float4*)&nbr[t * 4] = v;
    } else if (t < 192) {
        const int j = t - 128;
        const int a = j >> 4, k = j & 15;
        if (k < 15) {
            const float kx = kp[k*3+0], ky = kp[k*3+1], kz = kp[k*3+2];
            const float* R = anchors + a * 9;
            float4 v;
            v.x = R[0]*kx + R[1]*ky + R[2]*kz;
            v.y = R[3]*kx + R[4]*ky + R[5]*kz;
            v.z = R[6]*kx + R[7]*ky + R[8]*kz;
            v.w = v.x*v.x + v.y*v.y + v.z*v.z;
            *(float4*)&rk_s[(a * 16 + k) * 4] = v;
        }
    }
    __syncthreads();

    // ---------------- P2: gather x -> xa_s[a][q][c][b'] (bf16, transposed) ----------------
    // lane: c4 = t&7 (8 float4 per row-slice), bg = (t>>3)&7 (b-group of 4), q = t>>6.
    // b-block swizzle: b' = (b&7) | (((b>>3) ^ ((c>>2)&3)) << 3)  — breaks store conflicts,
    // reads stay 8-contiguous at block (quad ^ fc).
    {
        const int c4 = t & 7, bg = (t >> 3) & 7, q = t >> 6;
        #pragma unroll
        for (int a = 0; a < 4; ++a) {
            float4 v[4];
            #pragma unroll
            for (int i = 0; i < 4; ++i) {
                const int row = sidx[q * 32 + 4 * bg + i];
                v[i] = ((const float4*)x)[row * 32 + a * 8 + c4];
            }
            const float* vp = (const float*)v;
            #pragma unroll
            for (int j = 0; j < 4; ++j) {
                const int c  = 4 * c4 + j;
                const int fc = c4 & 3;                      // (c>>2)&3
                const int bb = 4 * (bg & 1) + 8 * ((bg >> 1) ^ fc);
                ushort4 w;
                w.x = f2bf(vp[0 * 4 + j]);
                w.y = f2bf(vp[1 * 4 + j]);
                w.z = f2bf(vp[2 * 4 + j]);
                w.w = f2bf(vp[3 * 4 + j]);
                *(ushort4*)&xa_s[((a * 4 + q) * 32 + c) * 32 + bb] = w;
            }
        }
    }

    // ---------------- P1: aw_s[a][q][k][b] = bf16 influence weights ----------------
    {
        #pragma unroll
        for (int i = 0; i < 2; ++i) {
            const int tau = i * 256 + t;
            const int a = tau >> 7, q = (tau >> 5) & 3, b = tau & 31;
            const float4 nb = *(const float4*)&nbr[(q * 32 + b) * 4];
            unsigned short wv[16];
            #pragma unroll
            for (int k = 0; k < 15; ++k) {
                const float4 r = *(const float4*)&rk_s[(a * 16 + k) * 4];
                const float sq = nb.w + r.w - 2.0f * (nb.x*r.x + nb.y*r.y + nb.z*r.z);
                const float d = sqrtf(fmaxf(sq, 1e-12f));
                wv[k] = f2bf(fmaxf(1.0f - d * (1.0f / 0.6f), 0.0f));
            }
            wv[15] = 0;
            unsigned short* p = &aw_s[(a * 4 + q) * 512 + b];
            #pragma unroll
            for (int k = 0; k < 16; ++k) p[k * 32] = wv[k];
        }
    }
    __syncthreads();

    // ---------------- Per-wave: anchor a = wave id ----------------
    const int a    = t >> 6;
    const int lane = t & 63;
    const int l15  = lane & 15;
    const int quad = lane >> 4;

    unsigned short* wfb = &xa_s[a * 4096];   // wf[q][c*16+k] bf16, aliases xa_s[a]

    // GEMM1: per q, wf[k,c] = sum_b aw[b,k]*x[b,c]
    // A[m=k][b]: aw_s[a][q][l15][quad*8..], B[b][n=c]: xa_s[a][q][c][(quad^fc)*8..]
    #pragma unroll
    for (int q = 0; q < 4; ++q) {
        const bf16x8 afr = *(const bf16x8*)&aw_s[((a * 4 + q) * 16 + l15) * 32 + quad * 8];
        const int fc  = (l15 >> 2) & 3;     // same for c=l15 and c=l15+16
        const bf16x8 b0 = *(const bf16x8*)&xa_s[((a * 4 + q) * 32 + l15) * 32 + 8 * (quad ^ fc)];
        const bf16x8 b1 = *(const bf16x8*)&xa_s[((a * 4 + q) * 32 + l15 + 16) * 32 + 8 * (quad ^ fc)];
        f32x4 d0 = {0.f, 0.f, 0.f, 0.f}, d1 = {0.f, 0.f, 0.f, 0.f};
        d0 = __builtin_amdgcn_mfma_f32_16x16x32_bf16(afr, b0, d0, 0, 0, 0);
        d1 = __builtin_amdgcn_mfma_f32_16x16x32_bf16(afr, b1, d1, 0, 0, 0);
        // D: col c = l15 (+16), rows k = quad*4 + reg -> wf[q][c][k], 4 contiguous k
        ushort4 s0, s1;
        s0.x = f2bf(d0[0]); s0.y = f2bf(d0[1]); s0.z = f2bf(d0[2]); s0.w = f2bf(d0[3]);
        s1.x = f2bf(d1[0]); s1.y = f2bf(d1[1]); s1.z = f2bf(d1[2]); s1.w = f2bf(d1[3]);
        *(ushort4*)&wfb[q * 512 + l15 * 16 + quad * 4]        = s0;
        *(ushort4*)&wfb[q * 512 + (l15 + 16) * 16 + quad * 4] = s1;
    }
    // no barrier: wf region is wave-private (only wave a reads xa_s[a])

    // GEMM2: out[q,d] = sum_{kc} wf[q,kc] * W[kc,d];  A rows m=0..15 -> q=m&3 (broadcast)
    f32x4 o0 = {0.f, 0.f, 0.f, 0.f}, o1 = {0.f, 0.f, 0.f, 0.f};
    #pragma unroll
    for (int kk = 0; kk < 16; ++kk) {
        const bf16x8 a2 = *(const bf16x8*)&wfb[(l15 & 3) * 512 + kk * 32 + quad * 8];
        const bf16x8 w0 = *(const bf16x8*)&Wp[kk * 1024 + l15 * 32 + quad * 8];
        const bf16x8 w1 = *(const bf16x8*)&Wp[kk * 1024 + (l15 + 16) * 32 + quad * 8];
        o0 = __builtin_amdgcn_mfma_f32_16x16x32_bf16(a2, w0, o0, 0, 0, 0);
        o1 = __builtin_amdgcn_mfma_f32_16x16x32_bf16(a2, w1, o1, 0, 0, 0);
    }
    // D: col d = l15 (+16), rows = quad*4+reg; only quad 0 (rows 0..3 = q) stores
    if (quad == 0) {
        #pragma unroll
        for (int r = 0; r < 4; ++r) {
            out[((n0 + r) * 4 + a) * 32 + l15]      = o0[r];
            out[((n0 + r) * 4 + a) * 32 + 16 + l15] = o1[r];
        }
    }
}

extern "C" void kernel_launch(void* const* d_in, const int* in_sizes, int n_in,
                              void* d_out, int out_size, void* d_ws, size_t ws_size,
                              hipStream_t stream) {
    const float* q_pts   = (const float*)d_in[0];
    const float* s_pts   = (const float*)d_in[1];
    const int*   inds    = (const int*)d_in[2];
    const float* x       = (const float*)d_in[3];
    const float* kp      = (const float*)d_in[4];
    const float* anchors = (const float*)d_in[5];
    const float* weights = (const float*)d_in[6];
    float*       out     = (float*)d_out;
    unsigned short* Wp   = (unsigned short*)d_ws;   // 32 KB

    prep_kernel<<<dim3(1), dim3(256), 0, stream>>>(weights, Wp);
    kpconv_mfma<<<dim3(4000), dim3(256), 0, stream>>>(
        q_pts, s_pts, inds, x, kp, anchors, Wp, out);
}

// Round 3
// 126.740 us; speedup vs baseline: 1.6301x; 1.1102x over previous
//
#include <hip/hip_runtime.h>

// KPConvInterSO3 via MFMA. N=16000, NB=32, A=4, K=15, CIN=COUT=32.
// Block = 256 threads = 4 waves; block handles 4 queries; wave w owns anchor w.
// GEMM1 per (q,a): wf[k,c] = sum_b aw[b,k] x[b,c]   (16x32, K=32) -> 2 MFMA
// GEMM2 per a:     out[q,d] = sum_{kc} wf[q,kc] W[kc,d] (16x32, K=512) -> 32 MFMA
// W pre-permuted to B-fragment layout (bf16) in d_ws by prep_kernel (64 blocks!).

typedef short bf16x8 __attribute__((ext_vector_type(8)));
typedef float f32x4  __attribute__((ext_vector_type(4)));

// round-half-up bf16: 2 VALU ops (vs 4-5 for RNE). <=1 ulp difference on ties.
__device__ __forceinline__ unsigned short f2bf(float f) {
    unsigned u = __builtin_bit_cast(unsigned, f);
    return (unsigned short)((u + 0x8000u) >> 16);
}

// pack two floats -> (bf(hi)<<16)|bf(lo) in 3 VALU ops via v_perm_b32
__device__ __forceinline__ unsigned pack2bf(float hi, float lo) {
    unsigned uh = __builtin_bit_cast(unsigned, hi) + 0x8000u;
    unsigned ul = __builtin_bit_cast(unsigned, lo) + 0x8000u;
    return __builtin_amdgcn_perm(uh, ul, 0x07060302u);
}

// Wp[kk][d][e] = bf16(W[k][c][d]), kcs' = kk*32+e = c*16+k (k=15 -> 0 pad).
// B-frag for GEMM2 step kk: lane reads 8 contiguous bf16 at [kk][d][quad*8].
// 64 blocks x 256 threads, one element each.
__global__ void prep_kernel(const float* __restrict__ W, unsigned short* __restrict__ Wp) {
    const int idx = blockIdx.x * 256 + threadIdx.x;   // 0..16383
    const int kk = idx >> 10, d = (idx >> 5) & 31, e = idx & 31;
    const int kcs = kk * 32 + e;
    const int c = kcs >> 4, k = kcs & 15;
    const float v = (k < 15) ? W[(k * 32 + c) * 32 + d] : 0.0f;
    Wp[idx] = f2bf(v);
}

__global__ __launch_bounds__(256) void kpconv_mfma(
    const float* __restrict__ q_pts,    // [N,3]
    const float* __restrict__ s_pts,    // [M,3]
    const int*   __restrict__ inds,     // [N,32]
    const float* __restrict__ x,        // [M,4,32]
    const float* __restrict__ kp,       // [15,3]
    const float* __restrict__ anchors,  // [4,3,3]
    const unsigned short* __restrict__ Wp, // [16][32][32] bf16 (permuted)
    float*       __restrict__ out)      // [N,4,32]
{
    // xa_s: [a][q][c][b_phys] bf16, 32KB. Per-a 4KB slice; after GEMM1 the
    // first 1KB-per-q is reused (wave-private, in order) as wf[q][c*16+k] bf16.
    __shared__ __align__(16) unsigned short xa_s[16384];
    __shared__ __align__(16) unsigned short aw_s[8192];   // [a][q][k][b] bf16, 16KB
    __shared__ __align__(16) float nbr[512];              // [q][b] float4 (dx,dy,dz,|d|^2)
    __shared__ __align__(16) float rk_s[256];             // [a][k] float4 (rx,ry,rz,|r|^2)
    __shared__ int sidx[128];                             // [q][b]

    const int t  = threadIdx.x;
    const int n0 = blockIdx.x * 4;

    // ---------------- P0: neighbors + rotated kernel points ----------------
    if (t < 128) {
        const int q = t >> 5, b = t & 31;
        const int idx = inds[(n0 + q) * 32 + b];
        sidx[t] = idx;
        const float qx = q_pts[(n0 + q) * 3 + 0];
        const float qy = q_pts[(n0 + q) * 3 + 1];
        const float qz = q_pts[(n0 + q) * 3 + 2];
        const float nx = s_pts[idx * 3 + 0] - qx;
        const float ny = s_pts[idx * 3 + 1] - qy;
        const float nz = s_pts[idx * 3 + 2] - qz;
        float4 v; v.x = nx; v.y = ny; v.z = nz; v.w = nx*nx + ny*ny + nz*nz;
        *(float4*)&nbr[t * 4] = v;
    } else if (t < 192) {
        const int j = t - 128;
        const int a = j >> 4, k = j & 15;
        if (k < 15) {
            const float kx = kp[k*3+0], ky = kp[k*3+1], kz = kp[k*3+2];
            const float* R = anchors + a * 9;
            float4 v;
            v.x = R[0]*kx + R[1]*ky + R[2]*kz;
            v.y = R[3]*kx + R[4]*ky + R[5]*kz;
            v.z = R[6]*kx + R[7]*ky + R[8]*kz;
            v.w = v.x*v.x + v.y*v.y + v.z*v.z;
            *(float4*)&rk_s[(a * 16 + k) * 4] = v;
        }
    }
    __syncthreads();

    // ---------------- P2: gather x -> xa_s[a][q][c][b'] (bf16, transposed) ----------------
    // lane: c4 = t&7 (8 float4 per row-slice), bg = (t>>3)&7 (b-group of 4), q = t>>6.
    // b-block swizzle: b' = (b&7) | (((b>>3) ^ ((c>>2)&3)) << 3)  — breaks store conflicts,
    // reads stay 8-contiguous at block (quad ^ fc).
    {
        const int c4 = t & 7, bg = (t >> 3) & 7, q = t >> 6;
        #pragma unroll
        for (int a = 0; a < 4; ++a) {
            float4 v[4];
            #pragma unroll
            for (int i = 0; i < 4; ++i) {
                const int row = sidx[q * 32 + 4 * bg + i];
                v[i] = ((const float4*)x)[row * 32 + a * 8 + c4];
            }
            const float* vp = (const float*)v;
            #pragma unroll
            for (int j = 0; j < 4; ++j) {
                const int c  = 4 * c4 + j;
                const int fc = c4 & 3;                      // (c>>2)&3
                const int bb = 4 * (bg & 1) + 8 * ((bg >> 1) ^ fc);
                uint2 w;
                w.x = pack2bf(vp[1 * 4 + j], vp[0 * 4 + j]);
                w.y = pack2bf(vp[3 * 4 + j], vp[2 * 4 + j]);
                *(uint2*)&xa_s[((a * 4 + q) * 32 + c) * 32 + bb] = w;
            }
        }
    }

    // ---------------- P1: aw_s[a][q][k][b] = bf16 influence weights ----------------
    {
        #pragma unroll
        for (int i = 0; i < 2; ++i) {
            const int tau = i * 256 + t;
            const int a = tau >> 7, q = (tau >> 5) & 3, b = tau & 31;
            const float4 nb = *(const float4*)&nbr[(q * 32 + b) * 4];
            unsigned short wv[16];
            #pragma unroll
            for (int k = 0; k < 15; ++k) {
                const float4 r = *(const float4*)&rk_s[(a * 16 + k) * 4];
                const float sq = nb.w + r.w - 2.0f * (nb.x*r.x + nb.y*r.y + nb.z*r.z);
                const float d = sqrtf(fmaxf(sq, 1e-12f));
                wv[k] = f2bf(fmaxf(1.0f - d * (1.0f / 0.6f), 0.0f));
            }
            wv[15] = 0;
            unsigned short* p = &aw_s[(a * 4 + q) * 512 + b];
            #pragma unroll
            for (int k = 0; k < 16; ++k) p[k * 32] = wv[k];
        }
    }
    __syncthreads();

    // ---------------- Per-wave: anchor a = wave id ----------------
    const int a    = t >> 6;
    const int lane = t & 63;
    const int l15  = lane & 15;
    const int quad = lane >> 4;

    unsigned short* wfb = &xa_s[a * 4096];   // wf[q][c*16+k] bf16, aliases xa_s[a]

    // GEMM1: per q, wf[k,c] = sum_b aw[b,k]*x[b,c]
    // A[m=k][b]: aw_s[a][q][l15][quad*8..], B[b][n=c]: xa_s[a][q][c][(quad^fc)*8..]
    #pragma unroll
    for (int q = 0; q < 4; ++q) {
        const bf16x8 afr = *(const bf16x8*)&aw_s[((a * 4 + q) * 16 + l15) * 32 + quad * 8];
        const int fc  = (l15 >> 2) & 3;     // same for c=l15 and c=l15+16
        const bf16x8 b0 = *(const bf16x8*)&xa_s[((a * 4 + q) * 32 + l15) * 32 + 8 * (quad ^ fc)];
        const bf16x8 b1 = *(const bf16x8*)&xa_s[((a * 4 + q) * 32 + l15 + 16) * 32 + 8 * (quad ^ fc)];
        f32x4 d0 = {0.f, 0.f, 0.f, 0.f}, d1 = {0.f, 0.f, 0.f, 0.f};
        d0 = __builtin_amdgcn_mfma_f32_16x16x32_bf16(afr, b0, d0, 0, 0, 0);
        d1 = __builtin_amdgcn_mfma_f32_16x16x32_bf16(afr, b1, d1, 0, 0, 0);
        // D: col c = l15 (+16), rows k = quad*4 + reg -> wf[q][c][k], 4 contiguous k
        uint2 s0, s1;
        s0.x = pack2bf(d0[1], d0[0]); s0.y = pack2bf(d0[3], d0[2]);
        s1.x = pack2bf(d1[1], d1[0]); s1.y = pack2bf(d1[3], d1[2]);
        *(uint2*)&wfb[q * 512 + l15 * 16 + quad * 4]        = s0;
        *(uint2*)&wfb[q * 512 + (l15 + 16) * 16 + quad * 4] = s1;
    }
    // no barrier: wf region is wave-private (only wave a reads xa_s[a])

    // GEMM2: out[q,d] = sum_{kc} wf[q,kc] * W[kc,d];  A rows m=0..15 -> q=m&3 (broadcast)
    f32x4 o0 = {0.f, 0.f, 0.f, 0.f}, o1 = {0.f, 0.f, 0.f, 0.f};
    #pragma unroll
    for (int kk = 0; kk < 16; ++kk) {
        const bf16x8 a2 = *(const bf16x8*)&wfb[(l15 & 3) * 512 + kk * 32 + quad * 8];
        const bf16x8 w0 = *(const bf16x8*)&Wp[kk * 1024 + l15 * 32 + quad * 8];
        const bf16x8 w1 = *(const bf16x8*)&Wp[kk * 1024 + (l15 + 16) * 32 + quad * 8];
        o0 = __builtin_amdgcn_mfma_f32_16x16x32_bf16(a2, w0, o0, 0, 0, 0);
        o1 = __builtin_amdgcn_mfma_f32_16x16x32_bf16(a2, w1, o1, 0, 0, 0);
    }
    // D: col d = l15 (+16), rows = quad*4+reg; only quad 0 (rows 0..3 = q) stores
    if (quad == 0) {
        #pragma unroll
        for (int r = 0; r < 4; ++r) {
            out[((n0 + r) * 4 + a) * 32 + l15]      = o0[r];
            out[((n0 + r) * 4 + a) * 32 + 16 + l15] = o1[r];
        }
    }
}

extern "C" void kernel_launch(void* const* d_in, const int* in_sizes, int n_in,
                              void* d_out, int out_size, void* d_ws, size_t ws_size,
                              hipStream_t stream) {
    const float* q_pts   = (const float*)d_in[0];
    const float* s_pts   = (const float*)d_in[1];
    const int*   inds    = (const int*)d_in[2];
    const float* x       = (const float*)d_in[3];
    const float* kp      = (const float*)d_in[4];
    const float* anchors = (const float*)d_in[5];
    const float* weights = (const float*)d_in[6];
    float*       out     = (float*)d_out;
    unsigned short* Wp   = (unsigned short*)d_ws;   // 32 KB

    prep_kernel<<<dim3(64), dim3(256), 0, stream>>>(weights, Wp);
    kpconv_mfma<<<dim3(4000), dim3(256), 0, stream>>>(
        q_pts, s_pts, inds, x, kp, anchors, Wp, out);
}

// Round 4
// 122.705 us; speedup vs baseline: 1.6837x; 1.0329x over previous
//
#include <hip/hip_runtime.h>

// KPConvInterSO3 via MFMA. N=16000, NB=32, A=4, K=15, CIN=COUT=32.
// Block = 256 threads = 4 waves; block handles 4 queries; wave w owns anchor w.
// GEMM1 per (q,a): wf[k,c] = sum_b aw[b,k] x[b,c]  — A-frag (influence weights)
//   computed IN REGISTERS (no aw LDS), B-frag from swizzled xa_s.
// GEMM2 per a: out[q,d] = sum_{kc} wf[q,kc] W[kc,d]; W pre-permuted (prep_kernel).
// LDS ~36.6 KB -> 4 blocks/CU (was 52.7 KB -> 3).

typedef short bf16x8 __attribute__((ext_vector_type(8)));
typedef float f32x4  __attribute__((ext_vector_type(4)));

// round-half-up bf16: 2 VALU ops. <=1 ulp difference vs RNE on ties.
__device__ __forceinline__ unsigned short f2bf(float f) {
    unsigned u = __builtin_bit_cast(unsigned, f);
    return (unsigned short)((u + 0x8000u) >> 16);
}

// pack two floats -> (bf(hi)<<16)|bf(lo) in 3 VALU ops via v_perm_b32
__device__ __forceinline__ unsigned pack2bf(float hi, float lo) {
    unsigned uh = __builtin_bit_cast(unsigned, hi) + 0x8000u;
    unsigned ul = __builtin_bit_cast(unsigned, lo) + 0x8000u;
    return __builtin_amdgcn_perm(uh, ul, 0x07060302u);
}

// Wp[kk][d][e] = bf16(W[k][c][d]), kcs = kk*32+e = c*16+k (k=15 -> 0 pad).
__global__ void prep_kernel(const float* __restrict__ W, unsigned short* __restrict__ Wp) {
    const int idx = blockIdx.x * 256 + threadIdx.x;   // 0..16383
    const int kk = idx >> 10, d = (idx >> 5) & 31, e = idx & 31;
    const int kcs = kk * 32 + e;
    const int c = kcs >> 4, k = kcs & 15;
    const float v = (k < 15) ? W[(k * 32 + c) * 32 + d] : 0.0f;
    Wp[idx] = f2bf(v);
}

__global__ __launch_bounds__(256) void kpconv_mfma(
    const float* __restrict__ q_pts,    // [N,3]
    const float* __restrict__ s_pts,    // [M,3]
    const int*   __restrict__ inds,     // [N,32]
    const float* __restrict__ x,        // [M,4,32]
    const float* __restrict__ kp,       // [15,3]
    const float* __restrict__ anchors,  // [4,3,3]
    const unsigned short* __restrict__ Wp, // [16][32][32] bf16 (permuted)
    float*       __restrict__ out)      // [N,4,32]
{
    // xa_s: [a][q][c][b_phys] bf16, 32KB; per-a slice later aliased (wave-private,
    // sequential) by wf[q] at q*512 + (kcs ^ (q*16)).
    __shared__ __align__(16) unsigned short xa_s[16384];
    // nbr: [q][b] float4 (dx,dy,dz,|d|^2), padded: float4 idx = q*36 + b + (b>>3)
    // so the 4 quads' b-octets start on different banks.
    __shared__ __align__(16) float nbr[576];
    __shared__ __align__(16) float rk_s[256];   // [a][k] float4 (rx,ry,rz,|r|^2); k=15 -> (0,0,0,1e30)
    __shared__ int sidx[128];                   // [q][b]

    const int t  = threadIdx.x;
    const int n0 = blockIdx.x * 4;

    // ---------------- P0: neighbors + rotated kernel points ----------------
    if (t < 128) {
        const int q = t >> 5, b = t & 31;
        const int idx = inds[(n0 + q) * 32 + b];
        sidx[t] = idx;
        const float qx = q_pts[(n0 + q) * 3 + 0];
        const float qy = q_pts[(n0 + q) * 3 + 1];
        const float qz = q_pts[(n0 + q) * 3 + 2];
        const float nx = s_pts[idx * 3 + 0] - qx;
        const float ny = s_pts[idx * 3 + 1] - qy;
        const float nz = s_pts[idx * 3 + 2] - qz;
        float4 v; v.x = nx; v.y = ny; v.z = nz; v.w = nx*nx + ny*ny + nz*nz;
        *(float4*)&nbr[(q * 36 + b + (b >> 3)) * 4] = v;
    } else if (t < 192) {
        const int j = t - 128;
        const int a = j >> 4, k = j & 15;
        float4 v;
        if (k < 15) {
            const float kx = kp[k*3+0], ky = kp[k*3+1], kz = kp[k*3+2];
            const float* R = anchors + a * 9;
            v.x = R[0]*kx + R[1]*ky + R[2]*kz;
            v.y = R[3]*kx + R[4]*ky + R[5]*kz;
            v.z = R[6]*kx + R[7]*ky + R[8]*kz;
            v.w = v.x*v.x + v.y*v.y + v.z*v.z;
        } else {
            v.x = 0.0f; v.y = 0.0f; v.z = 0.0f; v.w = 1e30f;  // kills k=15 row (w -> 0)
        }
        *(float4*)&rk_s[(a * 16 + k) * 4] = v;
    }
    __syncthreads();

    // ---------------- P2: gather x -> xa_s[a][q][c][b'] (bf16, transposed) ----------------
    // b-block swizzle: b' = (b&7) | (((b>>3) ^ ((c>>2)&3)) << 3) — conflict-free
    // stores; B-frag reads land at block (quad ^ fc).
    {
        const int c4 = t & 7, bg = (t >> 3) & 7, q = t >> 6;
        #pragma unroll
        for (int a = 0; a < 4; ++a) {
            float4 v[4];
            #pragma unroll
            for (int i = 0; i < 4; ++i) {
                const int row = sidx[q * 32 + 4 * bg + i];
                v[i] = ((const float4*)x)[row * 32 + a * 8 + c4];
            }
            const float* vp = (const float*)v;
            #pragma unroll
            for (int j = 0; j < 4; ++j) {
                const int c  = 4 * c4 + j;
                const int fc = c4 & 3;                      // (c>>2)&3
                const int bb = 4 * (bg & 1) + 8 * ((bg >> 1) ^ fc);
                uint2 w;
                w.x = pack2bf(vp[1 * 4 + j], vp[0 * 4 + j]);
                w.y = pack2bf(vp[3 * 4 + j], vp[2 * 4 + j]);
                *(uint2*)&xa_s[((a * 4 + q) * 32 + c) * 32 + bb] = w;
            }
        }
    }
    __syncthreads();

    // ---------------- Per-wave: anchor a = wave id ----------------
    const int a    = t >> 6;
    const int lane = t & 63;
    const int l15  = lane & 15;
    const int quad = lane >> 4;
    const int fc   = (l15 >> 2) & 3;

    const float4 r4 = *(const float4*)&rk_s[(a * 16 + l15) * 4];
    unsigned short* wfb = &xa_s[a * 4096];

    // GEMM1: per q, wf[k,c] = sum_b aw[b,k]*x[b,c].
    // A-frag in registers: lane (k=l15, b=quad*8+j) computes weight(q,a,b,k).
    #pragma unroll
    for (int q = 0; q < 4; ++q) {
        float w8[8];
        #pragma unroll
        for (int j = 0; j < 8; ++j) {
            const int b = quad * 8 + j;
            const float4 nb = *(const float4*)&nbr[(q * 36 + b + (b >> 3)) * 4];
            const float dot = fmaf(nb.x, r4.x, fmaf(nb.y, r4.y, nb.z * r4.z));
            const float sq  = fmaf(-2.0f, dot, nb.w + r4.w);
            const float d   = sqrtf(fmaxf(sq, 1e-12f));
            w8[j] = fmaxf(fmaf(d, -(1.0f / 0.6f), 1.0f), 0.0f);
        }
        uint4 uu;
        uu.x = pack2bf(w8[1], w8[0]); uu.y = pack2bf(w8[3], w8[2]);
        uu.z = pack2bf(w8[5], w8[4]); uu.w = pack2bf(w8[7], w8[6]);
        const bf16x8 afr = __builtin_bit_cast(bf16x8, uu);

        const bf16x8 b0 = *(const bf16x8*)&xa_s[((a*4 + q)*32 + l15)      * 32 + 8 * (quad ^ fc)];
        const bf16x8 b1 = *(const bf16x8*)&xa_s[((a*4 + q)*32 + l15 + 16) * 32 + 8 * (quad ^ fc)];
        f32x4 d0 = {0.f,0.f,0.f,0.f}, d1 = {0.f,0.f,0.f,0.f};
        d0 = __builtin_amdgcn_mfma_f32_16x16x32_bf16(afr, b0, d0, 0, 0, 0);
        d1 = __builtin_amdgcn_mfma_f32_16x16x32_bf16(afr, b1, d1, 0, 0, 0);
        // D: col c = l15 (+16), rows k = quad*4+reg. Store at
        // q*512 + (kcs ^ (q*16)), kcs = c*16 + k  (XOR-q spreads GEMM2 A-reads).
        uint2 s0, s1;
        s0.x = pack2bf(d0[1], d0[0]); s0.y = pack2bf(d0[3], d0[2]);
        s1.x = pack2bf(d1[1], d1[0]); s1.y = pack2bf(d1[3], d1[2]);
        *(uint2*)&wfb[q*512 + (( l15       * 16 + quad * 4) ^ (q * 16))] = s0;
        *(uint2*)&wfb[q*512 + (((l15 + 16) * 16 + quad * 4) ^ (q * 16))] = s1;
    }
    // no barrier: xa_s[a] is wave-private after the P2 barrier

    // GEMM2: out[q,d] = sum_{kc} wf[q,kc] * W[kc,d]; A rows m -> q = m&3
    const int qq = l15 & 3;
    f32x4 o0 = {0.f,0.f,0.f,0.f}, o1 = {0.f,0.f,0.f,0.f};
    #pragma unroll
    for (int kk = 0; kk < 16; ++kk) {
        const bf16x8 a2 = *(const bf16x8*)&wfb[qq*512 + ((kk*32 + quad*8) ^ (qq*16))];
        const bf16x8 w0 = *(const bf16x8*)&Wp[kk*1024 + l15*32 + quad*8];
        const bf16x8 w1 = *(const bf16x8*)&Wp[kk*1024 + (l15+16)*32 + quad*8];
        o0 = __builtin_amdgcn_mfma_f32_16x16x32_bf16(a2, w0, o0, 0, 0, 0);
        o1 = __builtin_amdgcn_mfma_f32_16x16x32_bf16(a2, w1, o1, 0, 0, 0);
    }
    // D: col d = l15 (+16), rows = quad*4+reg; quad 0 rows 0..3 = q
    if (quad == 0) {
        #pragma unroll
        for (int r = 0; r < 4; ++r) {
            out[((n0 + r) * 4 + a) * 32 + l15]      = o0[r];
            out[((n0 + r) * 4 + a) * 32 + 16 + l15] = o1[r];
        }
    }
}

extern "C" void kernel_launch(void* const* d_in, const int* in_sizes, int n_in,
                              void* d_out, int out_size, void* d_ws, size_t ws_size,
                              hipStream_t stream) {
    const float* q_pts   = (const float*)d_in[0];
    const float* s_pts   = (const float*)d_in[1];
    const int*   inds    = (const int*)d_in[2];
    const float* x       = (const float*)d_in[3];
    const float* kp      = (const float*)d_in[4];
    const float* anchors = (const float*)d_in[5];
    const float* weights = (const float*)d_in[6];
    float*       out     = (float*)d_out;
    unsigned short* Wp   = (unsigned short*)d_ws;   // 32 KB

    prep_kernel<<<dim3(64), dim3(256), 0, stream>>>(weights, Wp);
    kpconv_mfma<<<dim3(4000), dim3(256), 0, stream>>>(
        q_pts, s_pts, inds, x, kp, anchors, Wp, out);
}